// Round 9
// baseline (64.525 us; speedup 1.0000x reference)
//
#include <hip/hip_runtime.h>
#include <math.h>

#define D 256          // feature dim (fixed by reference)
#define NREL 16        // relation count
#define CHUNK 6250     // nodes per dst-chunk (2 x f32 LDS arrays = 50 KB)
#define BPC 32         // blocks per chunk (edge-slice parallelism)

typedef float f4v __attribute__((ext_vector_type(4)));

// ---------------------------------------------------------------------------
// Kernel A v5: y[n][r] = dot(x[n], W[r]) r<16, xr[n] = dot(x[n], root).
// NO LDS, NO barriers. Wave handles 8 nodes: 16-lane group g owns nodes
// (base+g, base+4+g); lane slot s=lane&15 owns d-elements {k*64+s*4..+4}
// (16 lanes x 16B = 256B coalesced segments). W/root (17 KB) stay L1-hot and
// are reused for both nodes. Cross-lane: 4-step __shfl_xor butterfly per
// accumulator within the 16-lane group, then cndmask-select + 64B row store.
// ---------------------------------------------------------------------------
__global__ __launch_bounds__(256) void rgcn_y_kernel(
    const float* __restrict__ x, const float* __restrict__ w,
    const float* __restrict__ root, float* __restrict__ y,
    float* __restrict__ xr, int n)
{
    const int t    = threadIdx.x;
    const int lane = t & 63;
    const int wv   = t >> 6;          // wave 0..3
    const int grp  = lane >> 4;       // node subgroup 0..3
    const int s    = lane & 15;       // d-slot 0..15
    const int node0 = blockIdx.x * 32 + wv * 8 + grp;
    const int node1 = node0 + 4;

    float accA[NREL + 1], accB[NREL + 1];
    #pragma unroll
    for (int r = 0; r <= NREL; ++r) { accA[r] = 0.f; accB[r] = 0.f; }

    const bool okA = (node0 < n);
    const bool okB = (node1 < n);
    const float* xrowA = x + (size_t)node0 * D;
    const float* xrowB = x + (size_t)node1 * D;

    #pragma unroll
    for (int k = 0; k < 4; ++k) {
        const int off = k * 64 + s * 4;
        float4 xa = make_float4(0.f, 0.f, 0.f, 0.f);
        float4 xb = make_float4(0.f, 0.f, 0.f, 0.f);
        if (okA) xa = *reinterpret_cast<const float4*>(xrowA + off);
        if (okB) xb = *reinterpret_cast<const float4*>(xrowB + off);
        #pragma unroll
        for (int r = 0; r < NREL; ++r) {
            float4 wv4 = *reinterpret_cast<const float4*>(
                             w + (size_t)r * D + off);
            accA[r] = fmaf(xa.x, wv4.x, accA[r]);
            accA[r] = fmaf(xa.y, wv4.y, accA[r]);
            accA[r] = fmaf(xa.z, wv4.z, accA[r]);
            accA[r] = fmaf(xa.w, wv4.w, accA[r]);
            accB[r] = fmaf(xb.x, wv4.x, accB[r]);
            accB[r] = fmaf(xb.y, wv4.y, accB[r]);
            accB[r] = fmaf(xb.z, wv4.z, accB[r]);
            accB[r] = fmaf(xb.w, wv4.w, accB[r]);
        }
        float4 rv = *reinterpret_cast<const float4*>(root + off);
        accA[NREL] = fmaf(xa.x, rv.x, accA[NREL]);
        accA[NREL] = fmaf(xa.y, rv.y, accA[NREL]);
        accA[NREL] = fmaf(xa.z, rv.z, accA[NREL]);
        accA[NREL] = fmaf(xa.w, rv.w, accA[NREL]);
        accB[NREL] = fmaf(xb.x, rv.x, accB[NREL]);
        accB[NREL] = fmaf(xb.y, rv.y, accB[NREL]);
        accB[NREL] = fmaf(xb.z, rv.z, accB[NREL]);
        accB[NREL] = fmaf(xb.w, rv.w, accB[NREL]);
    }

    // butterfly all-reduce within each 16-lane group
    #pragma unroll
    for (int r = 0; r <= NREL; ++r) {
        #pragma unroll
        for (int m = 8; m >= 1; m >>= 1) {
            accA[r] += __shfl_xor(accA[r], m, 16);
            accB[r] += __shfl_xor(accB[r], m, 16);
        }
    }

    // lane s takes relation r == s (cndmask chain, static indexing)
    float ya = accA[0], yb = accB[0];
    #pragma unroll
    for (int r = 1; r < NREL; ++r) {
        if (s == r) { ya = accA[r]; yb = accB[r]; }
    }

    if (okA) {
        y[(size_t)node0 * NREL + s] = ya;
        if (s == 0) xr[node0] = accA[NREL];
    }
    if (okB) {
        y[(size_t)node1 * NREL + s] = yb;
        if (s == 0) xr[node1] = accB[NREL];
    }
}

// ---------------------------------------------------------------------------
// Kernel B: chunked edge scan, LDS accumulation, zero global atomics.
// Unconditional int4 loads of dst/src/et (3 independent vector loads per
// 4-edge group -> deep memory-level parallelism).
// ---------------------------------------------------------------------------
__global__ __launch_bounds__(1024) void rgcn_edge_scan_kernel(
    const int* __restrict__ src, const int* __restrict__ dst,
    const int* __restrict__ et, const float* __restrict__ y,
    float2* __restrict__ partial, int e, int sl)
{
    __shared__ float lsum[CHUNK];
    __shared__ float lcnt[CHUNK];
    const int t = threadIdx.x;
    const int c = blockIdx.x / BPC;
    const int b = blockIdx.x % BPC;
    const int base = c * CHUNK;

    for (int j = t; j < CHUNK; j += 1024) { lsum[j] = 0.f; lcnt[j] = 0.f; }
    __syncthreads();

    const int slice0 = b * sl;
    const int rem = e - slice0;
    if (rem > 0) {
        const int gmax = (min(sl, rem) + 3) >> 2;   // int4 groups in slice
        for (int g = t; g < gmax; g += 1024) {
            int idx = slice0 + g * 4;
            if (idx + 3 < e) {
                int4 d4 = *reinterpret_cast<const int4*>(dst + idx);
                int4 s4 = *reinterpret_cast<const int4*>(src + idx);
                int4 r4 = *reinterpret_cast<const int4*>(et + idx);
                int loc0 = d4.x - base, loc1 = d4.y - base;
                int loc2 = d4.z - base, loc3 = d4.w - base;
                if ((unsigned)loc0 < (unsigned)CHUNK) {
                    atomicAdd(&lsum[loc0], y[(size_t)s4.x * NREL + r4.x]);
                    atomicAdd(&lcnt[loc0], 1.0f);
                }
                if ((unsigned)loc1 < (unsigned)CHUNK) {
                    atomicAdd(&lsum[loc1], y[(size_t)s4.y * NREL + r4.y]);
                    atomicAdd(&lcnt[loc1], 1.0f);
                }
                if ((unsigned)loc2 < (unsigned)CHUNK) {
                    atomicAdd(&lsum[loc2], y[(size_t)s4.z * NREL + r4.z]);
                    atomicAdd(&lcnt[loc2], 1.0f);
                }
                if ((unsigned)loc3 < (unsigned)CHUNK) {
                    atomicAdd(&lsum[loc3], y[(size_t)s4.w * NREL + r4.w]);
                    atomicAdd(&lcnt[loc3], 1.0f);
                }
            } else {
                for (int k = idx; k < e; ++k) {
                    int loc = dst[k] - base;
                    if ((unsigned)loc < (unsigned)CHUNK) {
                        atomicAdd(&lsum[loc], y[(size_t)src[k] * NREL + et[k]]);
                        atomicAdd(&lcnt[loc], 1.0f);
                    }
                }
            }
        }
    }
    __syncthreads();

    float2* p = partial + ((size_t)(c * BPC + b)) * CHUNK;
    for (int j = t; j < CHUNK; j += 1024)
        p[j] = make_float2(lsum[j], lcnt[j]);
}

// ---------------------------------------------------------------------------
// Kernel C (fused finish), 32 nodes/block:
//   phase 1 (ALL threads): thread t reduces 4 partials of node t&31
//                          (b-group t>>5), LDS-atomic combine;
//                          then 32 threads do tanh -> sc[] + out_score.
//   phase 2 (all):  x_out = x * score, nontemporal float4 stores.
// ---------------------------------------------------------------------------
__global__ __launch_bounds__(256) void rgcn_finish_kernel(
    const float2* __restrict__ partial, const float* __restrict__ xr,
    const float* __restrict__ bias, const float* __restrict__ x,
    float* __restrict__ out_x, float* __restrict__ out_score, int n)
{
    __shared__ float ssum[32], scnt[32], sc[32];
    const int t = threadIdx.x;
    const int base = blockIdx.x * 32;

    if (t < 32) { ssum[t] = 0.f; scnt[t] = 0.f; }
    __syncthreads();

    {
        int nl = t & 31;
        int bg = t >> 5;                 // 0..7, covers BPC=32 in 4s
        int node = base + nl;
        float s = 0.f, cN = 0.f;
        if (node < n) {
            int c = node / CHUNK;
            int j = node - c * CHUNK;
            const float2* p = partial + (size_t)c * BPC * CHUNK + j;
            #pragma unroll
            for (int b = 0; b < 4; ++b) {
                float2 v = p[(size_t)(bg * 4 + b) * CHUNK];
                s += v.x; cN += v.y;
            }
        }
        atomicAdd(&ssum[nl], s);
        atomicAdd(&scnt[nl], cN);
    }
    __syncthreads();

    if (t < 32) {
        int node = base + t;
        if (node < n) {
            float m = ssum[t] / fmaxf(scnt[t], 1.0f);
            float v = tanhf(m + xr[node] + bias[0]);
            sc[t] = v;
            out_score[node] = v;
        }
    }
    __syncthreads();

    #pragma unroll
    for (int k = 0; k < 8; ++k) {
        int nl = k * 4 + (t >> 6);       // node local 0..31
        int f4 = t & 63;                 // float4 index in row
        int node = base + nl;
        if (node < n) {
            float s = sc[nl];
            float4 v = *reinterpret_cast<const float4*>(
                           x + (size_t)node * D + f4 * 4);
            v.x *= s; v.y *= s; v.z *= s; v.w *= s;
            f4v vo = {v.x, v.y, v.z, v.w};
            __builtin_nontemporal_store(
                vo, (f4v*)(out_x + (size_t)node * D + f4 * 4));
        }
    }
}

// --------------------- fallback path (scratch in out tail) -----------------
__global__ __launch_bounds__(256) void rgcn_reduce_score_kernel(
    const float2* __restrict__ partial, const float* __restrict__ xr,
    const float* __restrict__ bias, float* __restrict__ score, int n)
{
    int i = blockIdx.x * 256 + threadIdx.x;
    if (i < n) {
        int c = i / CHUNK;
        int j = i - c * CHUNK;
        const float2* p = partial + (size_t)c * BPC * CHUNK + j;
        float s = 0.f, cN = 0.f;
        #pragma unroll 8
        for (int b = 0; b < BPC; ++b) {
            float2 v = p[(size_t)b * CHUNK];
            s += v.x; cN += v.y;
        }
        float m = s / fmaxf(cN, 1.0f);
        score[i] = tanhf(m + xr[i] + bias[0]);
    }
}

__global__ __launch_bounds__(256) void rgcn_scale_kernel(
    const float* __restrict__ x, const float* __restrict__ score,
    float* __restrict__ xo, int n)
{
    int gid = blockIdx.x * 256 + threadIdx.x;
    int node = gid >> 6;
    int f4 = gid & 63;
    if (node < n) {
        float s = score[node];
        float4 v = *reinterpret_cast<const float4*>(
                       x + (size_t)node * D + f4 * 4);
        v.x *= s; v.y *= s; v.z *= s; v.w *= s;
        *reinterpret_cast<float4*>(xo + (size_t)node * D + f4 * 4) = v;
    }
}

extern "C" void kernel_launch(void* const* d_in, const int* in_sizes, int n_in,
                              void* d_out, int out_size, void* d_ws, size_t ws_size,
                              hipStream_t stream)
{
    const float* x    = (const float*)d_in[0];
    const int*   ei   = (const int*)d_in[1];   // (2, E): src then dst
    const int*   et   = (const int*)d_in[2];
    const float* w    = (const float*)d_in[3]; // (R, D, 1) -> flat r*D+d
    const float* root = (const float*)d_in[4]; // (D, 1)    -> flat d
    const float* bias = (const float*)d_in[5];

    const int n = in_sizes[0] / D;   // 50000
    const int e = in_sizes[2];       // 800000

    float* out       = (float*)d_out;
    float* out_x     = out;                       // n*D floats
    float* out_score = out + (size_t)n * D;       // n floats

    const int C = (n + CHUNK - 1) / CHUNK;        // 8 for n=50000
    const int sl = ((((e + BPC - 1) / BPC) + 3) & ~3);  // slice len, mult of 4

    // Scratch: partials (C*BPC*CHUNK float2) | y (16n) | xr (n)
    const size_t part_f = (size_t)C * BPC * CHUNK * 2;   // floats
    const size_t need_f = part_f + (size_t)n * (NREL + 1);
    const bool use_ws = (ws_size >= need_f * sizeof(float));

    float* sb;
    if (use_ws)
        sb = (float*)d_ws;
    else {
        size_t ts = (((size_t)n * D - need_f) & ~(size_t)1);  // 8B-align
        sb = out_x + ts;
    }
    float2* partial = (float2*)sb;
    float*  y  = sb + part_f;
    float*  xr = y + (size_t)n * NREL;

    dim3 blk(256);
    rgcn_y_kernel<<<dim3((n + 31) / 32), blk, 0, stream>>>(x, w, root, y, xr, n);

    rgcn_edge_scan_kernel<<<dim3(C * BPC), dim3(1024), 0, stream>>>(
        ei, ei + e, et, y, partial, e, sl);

    if (use_ws) {
        rgcn_finish_kernel<<<dim3((n + 31) / 32), blk, 0, stream>>>(
            partial, xr, bias, x, out_x, out_score, n);
    } else {
        rgcn_reduce_score_kernel<<<dim3((n + 255) / 256), blk, 0, stream>>>(
            partial, xr, bias, out_score, n);
        rgcn_scale_kernel<<<dim3((int)(((size_t)n * 64 + 255) / 256)), blk, 0, stream>>>(
            x, out_score, out_x, n);
    }
}